// Round 1
// baseline (100.380 us; speedup 1.0000x reference)
//
#include <hip/hip_runtime.h>
#include <math.h>

// Problem constants (fixed by reference setup_inputs)
#define N_TOT   8192
#define M_TOT   16384
#define EPS_N   1024     // M / N_EMB
#define NBLK_I  32       // i-splits
#define I_CHUNK (N_TOT / NBLK_I)   // 256
#define BLOCK   256
#define NJ      4
#define J_CHUNK (BLOCK * NJ)       // 1024
#define NBLK_J  (M_TOT / J_CHUNK)  // 16

// log2(e), ln(2)
#define LOG2E 1.4426950408889634f
#define LN2   0.6931471805599453f

// Kernel 1: per (i-block, j-block) partial sums S_partial[j] = sum_{i in chunk} 2^(c_i + b0_i*e0_j + b1_i*e1_j)
__global__ __launch_bounds__(BLOCK) void partial_kernel(
    const float* __restrict__ z, const float* __restrict__ emb,
    const float* __restrict__ log_sigma, const float* __restrict__ eps,
    const float* __restrict__ temperature, float* __restrict__ part)
{
    __shared__ float4 zt[I_CHUNK];
    const int bid = blockIdx.x;
    const int jb  = bid & (NBLK_J - 1);
    const int ib  = bid >> 4;            // NBLK_J == 16
    const int t   = threadIdx.x;

    const float ls = log_sigma[0];
    const float T  = temperature[0];
    const float alpha = -0.5f * __expf(-2.0f * ls);   // -1/(2*sigma^2)
    const float La = LOG2E * alpha;

    // Stage per-i triples (c, b0, b1) for this block's i-chunk into LDS
    {
        int i = ib * I_CHUNK + t;
        float z0 = z[2 * i], z1 = z[2 * i + 1];
        zt[t] = make_float4(La * (z0 * z0 + z1 * z1),
                            -2.0f * La * z0,
                            -2.0f * La * z1, 0.0f);
    }

    // This thread's NJ sample points e_j (j = jbase + q*BLOCK, coalesced stores later)
    float e0[NJ], e1[NJ];
    const int jbase = jb * J_CHUNK + t;
    const float omT = 1.0f - T;
#pragma unroll
    for (int q = 0; q < NJ; ++q) {
        int j = jbase + q * BLOCK;
        int k = j >> 10;        // embedding index (EPS_N = 1024)
        int l = j & (EPS_N - 1);
        e0[q] = omT * emb[2 * k]     + T * eps[2 * l];
        e1[q] = omT * emb[2 * k + 1] + T * eps[2 * l + 1];
    }
    __syncthreads();

    float s[NJ] = {0.0f, 0.0f, 0.0f, 0.0f};
#pragma unroll 4
    for (int ii = 0; ii < I_CHUNK; ++ii) {
        float4 w = zt[ii];      // wave-uniform broadcast read (conflict-free)
#pragma unroll
        for (int q = 0; q < NJ; ++q) {
            float tt = fmaf(w.z, e1[q], fmaf(w.y, e0[q], w.x));
            s[q] += exp2f(tt);  // v_exp_f32 — trans pipe, the bottleneck
        }
    }

#pragma unroll
    for (int q = 0; q < NJ; ++q)
        part[ib * M_TOT + jbase + q * BLOCK] = s[q];
}

// Kernel 2: per-j combine partials, v_j = g_j + log2(S_j); block-sum -> bsum[block]
__global__ __launch_bounds__(BLOCK) void reduce_kernel(
    const float* __restrict__ emb, const float* __restrict__ log_sigma,
    const float* __restrict__ eps, const float* __restrict__ temperature,
    const float* __restrict__ part, float* __restrict__ bsum)
{
    const int j = blockIdx.x * BLOCK + threadIdx.x;
    const float ls = log_sigma[0];
    const float T  = temperature[0];
    const float alpha = -0.5f * __expf(-2.0f * ls);

    float S = 0.0f;
#pragma unroll
    for (int ib = 0; ib < NBLK_I; ++ib)
        S += part[ib * M_TOT + j];   // coalesced across threads

    const int k = j >> 10, l = j & (EPS_N - 1);
    const float omT = 1.0f - T;
    float e0 = omT * emb[2 * k]     + T * eps[2 * l];
    float e1 = omT * emb[2 * k + 1] + T * eps[2 * l + 1];
    float g  = LOG2E * alpha * (e0 * e0 + e1 * e1);   // factored-out 2^g term

    float v = g + log2f(S);          // lse_j / ln2

    // wave64 reduce, then cross-wave via LDS
#pragma unroll
    for (int off = 32; off; off >>= 1) v += __shfl_down(v, off, 64);
    __shared__ float wsum[BLOCK / 64];
    const int lane = threadIdx.x & 63, w = threadIdx.x >> 6;
    if (lane == 0) wsum[w] = v;
    __syncthreads();
    if (threadIdx.x == 0)
        bsum[blockIdx.x] = wsum[0] + wsum[1] + wsum[2] + wsum[3];
}

// Kernel 3: single wave — assemble scalar loss
__global__ void final_kernel(const float* __restrict__ log_sigma,
                             const float* __restrict__ bsum,
                             float* __restrict__ out)
{
    float v = bsum[threadIdx.x];     // exactly 64 block sums
#pragma unroll
    for (int off = 32; off; off >>= 1) v += __shfl_down(v, off, 64);
    if (threadIdx.x == 0) {
        const float ls = log_sigma[0];
        float sum_lse = v * LN2;                         // sum_j lse_j
        // loss = -mean(lse) + 0.5*z_dim*(2*ls - 1) + log(n);  z_dim=2, n=8192
        out[0] = -sum_lse / (float)M_TOT + (2.0f * ls - 1.0f) + 9.010913347279288f;
    }
}

extern "C" void kernel_launch(void* const* d_in, const int* in_sizes, int n_in,
                              void* d_out, int out_size, void* d_ws, size_t ws_size,
                              hipStream_t stream)
{
    const float* z    = (const float*)d_in[0];
    const float* emb  = (const float*)d_in[1];
    const float* lsig = (const float*)d_in[2];
    const float* eps  = (const float*)d_in[3];
    const float* temp = (const float*)d_in[4];

    float* part = (float*)d_ws;                    // NBLK_I * M_TOT floats = 2 MB
    float* bsum = part + (size_t)NBLK_I * M_TOT;   // 64 floats

    partial_kernel<<<NBLK_I * NBLK_J, BLOCK, 0, stream>>>(z, emb, lsig, eps, temp, part);
    reduce_kernel<<<M_TOT / BLOCK, BLOCK, 0, stream>>>(emb, lsig, eps, temp, part, bsum);
    final_kernel<<<1, 64, 0, stream>>>(lsig, bsum, (float*)d_out);
}

// Round 2
// 98.562 us; speedup vs baseline: 1.0184x; 1.0184x over previous
//
#include <hip/hip_runtime.h>
#include <math.h>

// Problem constants (fixed by reference setup_inputs)
#define N_TOT   8192
#define M_TOT   16384
#define EPS_N   1024     // M / N_EMB
#define NBLK_I  64       // i-splits  (R2: 32->64 for 4 waves/SIMD)
#define I_CHUNK (N_TOT / NBLK_I)   // 128
#define BLOCK   256
#define NJ      4
#define J_CHUNK (BLOCK * NJ)       // 1024
#define NBLK_J  (M_TOT / J_CHUNK)  // 16

// log2(e), ln(2)
#define LOG2E 1.4426950408889634f
#define LN2   0.6931471805599453f

// R2: raw v_exp_f32 — exp2f() without fast-math expands to a ~10-inst guarded
// sequence (R1 post-mortem: 4x the expected VALU issue). Args here are in
// [-80, 0]: no denormal-input/overflow edge cases, 1-ULP is plenty.
#define EXP2(x) __builtin_amdgcn_exp2f(x)

// Kernel 1: per (i-block, j-block) partial sums
// S_partial[j] = sum_{i in chunk} 2^(c_i + b0_i*e0_j + b1_i*e1_j)
__global__ __launch_bounds__(BLOCK) void partial_kernel(
    const float* __restrict__ z, const float* __restrict__ emb,
    const float* __restrict__ log_sigma, const float* __restrict__ eps,
    const float* __restrict__ temperature, float* __restrict__ part)
{
    __shared__ float4 zt[I_CHUNK];
    const int bid = blockIdx.x;
    const int jb  = bid & (NBLK_J - 1);
    const int ib  = bid >> 4;            // NBLK_J == 16
    const int t   = threadIdx.x;

    const float ls = log_sigma[0];
    const float T  = temperature[0];
    const float alpha = -0.5f * EXP2(LOG2E * (-2.0f * ls));   // -1/(2*sigma^2)
    const float La = LOG2E * alpha;

    // Stage per-i triples (c, b0, b1) for this block's i-chunk into LDS
    if (t < I_CHUNK) {
        int i = ib * I_CHUNK + t;
        float z0 = z[2 * i], z1 = z[2 * i + 1];
        zt[t] = make_float4(La * (z0 * z0 + z1 * z1),
                            -2.0f * La * z0,
                            -2.0f * La * z1, 0.0f);
    }

    // This thread's NJ sample points e_j
    float e0[NJ], e1[NJ];
    const int jbase = jb * J_CHUNK + t;
    const float omT = 1.0f - T;
#pragma unroll
    for (int q = 0; q < NJ; ++q) {
        int j = jbase + q * BLOCK;
        int k = j >> 10;        // embedding index (EPS_N = 1024)
        int l = j & (EPS_N - 1);
        e0[q] = omT * emb[2 * k]     + T * eps[2 * l];
        e1[q] = omT * emb[2 * k + 1] + T * eps[2 * l + 1];
    }
    __syncthreads();

    float s[NJ] = {0.0f, 0.0f, 0.0f, 0.0f};
#pragma unroll 4
    for (int ii = 0; ii < I_CHUNK; ++ii) {
        float4 w = zt[ii];      // wave-uniform broadcast read (conflict-free)
#pragma unroll
        for (int q = 0; q < NJ; ++q) {
            float tt = fmaf(w.z, e1[q], fmaf(w.y, e0[q], w.x));
            s[q] += EXP2(tt);   // single v_exp_f32 — trans pipe
        }
    }

#pragma unroll
    for (int q = 0; q < NJ; ++q)
        part[ib * M_TOT + jbase + q * BLOCK] = s[q];
}

// Kernel 2: per-j combine partials, v_j = g_j + log2(S_j); block-sum -> bsum[block]
__global__ __launch_bounds__(BLOCK) void reduce_kernel(
    const float* __restrict__ emb, const float* __restrict__ log_sigma,
    const float* __restrict__ eps, const float* __restrict__ temperature,
    const float* __restrict__ part, float* __restrict__ bsum)
{
    const int j = blockIdx.x * BLOCK + threadIdx.x;
    const float ls = log_sigma[0];
    const float T  = temperature[0];
    const float alpha = -0.5f * EXP2(LOG2E * (-2.0f * ls));

    float S = 0.0f;
#pragma unroll
    for (int ib = 0; ib < NBLK_I; ++ib)
        S += part[ib * M_TOT + j];   // coalesced across threads

    const int k = j >> 10, l = j & (EPS_N - 1);
    const float omT = 1.0f - T;
    float e0 = omT * emb[2 * k]     + T * eps[2 * l];
    float e1 = omT * emb[2 * k + 1] + T * eps[2 * l + 1];
    float g  = LOG2E * alpha * (e0 * e0 + e1 * e1);   // factored-out 2^g term

    float v = g + __builtin_amdgcn_logf(S);  // v_log_f32: log2(S); S is O(1), safe

    // wave64 reduce, then cross-wave via LDS
#pragma unroll
    for (int off = 32; off; off >>= 1) v += __shfl_down(v, off, 64);
    __shared__ float wsum[BLOCK / 64];
    const int lane = threadIdx.x & 63, w = threadIdx.x >> 6;
    if (lane == 0) wsum[w] = v;
    __syncthreads();
    if (threadIdx.x == 0)
        bsum[blockIdx.x] = wsum[0] + wsum[1] + wsum[2] + wsum[3];
}

// Kernel 3: single wave — assemble scalar loss
__global__ void final_kernel(const float* __restrict__ log_sigma,
                             const float* __restrict__ bsum,
                             float* __restrict__ out)
{
    float v = bsum[threadIdx.x];     // exactly 64 block sums
#pragma unroll
    for (int off = 32; off; off >>= 1) v += __shfl_down(v, off, 64);
    if (threadIdx.x == 0) {
        const float ls = log_sigma[0];
        float sum_lse = v * LN2;                         // sum_j lse_j
        // loss = -mean(lse) + 0.5*z_dim*(2*ls - 1) + log(n);  z_dim=2, n=8192
        out[0] = -sum_lse / (float)M_TOT + (2.0f * ls - 1.0f) + 9.010913347279288f;
    }
}

extern "C" void kernel_launch(void* const* d_in, const int* in_sizes, int n_in,
                              void* d_out, int out_size, void* d_ws, size_t ws_size,
                              hipStream_t stream)
{
    const float* z    = (const float*)d_in[0];
    const float* emb  = (const float*)d_in[1];
    const float* lsig = (const float*)d_in[2];
    const float* eps  = (const float*)d_in[3];
    const float* temp = (const float*)d_in[4];

    float* part = (float*)d_ws;                    // NBLK_I * M_TOT floats = 4 MB
    float* bsum = part + (size_t)NBLK_I * M_TOT;   // 64 floats

    partial_kernel<<<NBLK_I * NBLK_J, BLOCK, 0, stream>>>(z, emb, lsig, eps, temp, part);
    reduce_kernel<<<M_TOT / BLOCK, BLOCK, 0, stream>>>(emb, lsig, eps, temp, part, bsum);
    final_kernel<<<1, 64, 0, stream>>>(lsig, bsum, (float*)d_out);
}

// Round 3
// 73.955 us; speedup vs baseline: 1.3573x; 1.3327x over previous
//
#include <hip/hip_runtime.h>
#include <math.h>

// Problem constants (fixed by reference setup_inputs)
#define N_TOT 8192
#define M_TOT 16384
#define EPS_N 1024      // M / N_EMB
#define N_EMB 16

#define LOG2E 1.4426950408889634f
#define LN2   0.6931471805599453f
#define EXP2(x) __builtin_amdgcn_exp2f(x)   // v_exp_f32
#define LOG2F_(x) __builtin_amdgcn_logf(x)  // v_log_f32 (log2)

// K1 tiling: product-grid factorization e_j = m_k + T*u_l  (j = k*1024 + l)
//   t_ij = A_ik + B_il,  P=2^A (8192x16), Q=2^B (8192x1024), S_kl = sum_i P_ik Q_il
#define BLOCK 256
#define IC    128            // i's per block
#define NICH  (N_TOT / IC)   // 64 i-chunks
#define LCH   128            // l's per block
#define NLCH  (EPS_N / LCH)  // 8 l-chunks

__global__ __launch_bounds__(BLOCK) void gemm_partial_kernel(
    const float* __restrict__ z, const float* __restrict__ emb,
    const float* __restrict__ log_sigma, const float* __restrict__ eps,
    const float* __restrict__ temperature, float* __restrict__ part)
{
    // per i: slots 0..3 = P[k=0..15] as float4s, slot 4 = (T*b0, T*b1, -, -)
    __shared__ float4 rows[IC * 5];              // 10 KB
    __shared__ float red[4][N_EMB * LCH];        // 32 KB, per-wave partials

    const int t  = threadIdx.x;
    const int l0 = blockIdx.x * LCH;
    const int ib = blockIdx.y;

    const float ls = log_sigma[0];
    const float T  = temperature[0];
    const float alpha = -0.5f * EXP2(LOG2E * (-2.0f * ls));  // -1/(2 sigma^2)
    const float La  = LOG2E * alpha;
    const float omT = 1.0f - T;

    // Phase A: stage P-rows. 256 threads cover 128 i's x 2 k-halves (8 exps each).
    {
        const int il = t & (IC - 1);
        const int kh = t >> 7;                   // wave-uniform (waves 0,1 -> 0; 2,3 -> 1)
        const int i  = ib * IC + il;
        const float z0 = z[2 * i], z1 = z[2 * i + 1];
        const float c  = La * (z0 * z0 + z1 * z1);
        const float b0 = -2.0f * La * z0, b1 = -2.0f * La * z1;
        float4 pa, pb;
#pragma unroll
        for (int kk = 0; kk < 4; ++kk) {
            int k = kh * 8 + kk;
            float m0 = omT * emb[2 * k], m1 = omT * emb[2 * k + 1];
            ((float*)&pa)[kk] = EXP2(c + b0 * m0 + b1 * m1);   // P_ik
        }
#pragma unroll
        for (int kk = 0; kk < 4; ++kk) {
            int k = kh * 8 + 4 + kk;
            float m0 = omT * emb[2 * k], m1 = omT * emb[2 * k + 1];
            ((float*)&pb)[kk] = EXP2(c + b0 * m0 + b1 * m1);
        }
        rows[il * 5 + kh * 2]     = pa;
        rows[il * 5 + kh * 2 + 1] = pb;
        if (kh == 0)
            rows[il * 5 + 4] = make_float4(T * b0, T * b1, 0.0f, 0.0f);
    }

    // Each lane owns 2 l's: la = l0+lane, lb = la+64  (coalesced float2 loads)
    const int lane = t & 63;
    const int w    = t >> 6;
    const float2* eps2 = (const float2*)eps;
    const float2 ua = eps2[l0 + lane];
    const float2 ub = eps2[l0 + 64 + lane];

    __syncthreads();

    float sa[N_EMB] = {0.0f};
    float sb[N_EMB] = {0.0f};
    // Each wave reduces its private 32-i subrange; rows reads are wave-uniform (broadcast).
#pragma unroll 2
    for (int n = 0; n < IC / 4; ++n) {
        const int ir = w * (IC / 4) + n;
        float4 p0 = rows[ir * 5 + 0];
        float4 p1 = rows[ir * 5 + 1];
        float4 p2 = rows[ir * 5 + 2];
        float4 p3 = rows[ir * 5 + 3];
        float4 tb = rows[ir * 5 + 4];
        float qa = EXP2(fmaf(tb.y, ua.y, tb.x * ua.x));   // Q_i,la
        float qb = EXP2(fmaf(tb.y, ub.y, tb.x * ub.x));   // Q_i,lb
        float pk[16];
        *(float4*)&pk[0]  = p0; *(float4*)&pk[4]  = p1;
        *(float4*)&pk[8]  = p2; *(float4*)&pk[12] = p3;
#pragma unroll
        for (int k = 0; k < N_EMB; ++k) {
            sa[k] = fmaf(pk[k], qa, sa[k]);
            sb[k] = fmaf(pk[k], qb, sb[k]);
        }
    }

    // Phase C: cross-wave reduce via LDS (conflict-free: lane-contiguous)
#pragma unroll
    for (int k = 0; k < N_EMB; ++k) {
        red[w][k * LCH + lane]      = sa[k];
        red[w][k * LCH + 64 + lane] = sb[k];
    }
    __syncthreads();
#pragma unroll
    for (int r = 0; r < (N_EMB * LCH) / BLOCK; ++r) {
        const int e  = t + r * BLOCK;
        const float S = red[0][e] + red[1][e] + red[2][e] + red[3][e];
        const int k  = e >> 7;            // e / LCH
        const int lc = e & (LCH - 1);
        part[ib * M_TOT + k * EPS_N + l0 + lc] = S;
    }
}

// Kernel 2: per-j combine partials, v_j = g_j + log2(S_j); block-sum -> bsum[block]
__global__ __launch_bounds__(BLOCK) void reduce_kernel(
    const float* __restrict__ emb, const float* __restrict__ log_sigma,
    const float* __restrict__ eps, const float* __restrict__ temperature,
    const float* __restrict__ part, float* __restrict__ bsum)
{
    const int j = blockIdx.x * BLOCK + threadIdx.x;
    const float ls = log_sigma[0];
    const float T  = temperature[0];
    const float alpha = -0.5f * EXP2(LOG2E * (-2.0f * ls));

    float S = 0.0f;
#pragma unroll 8
    for (int ib = 0; ib < NICH; ++ib)
        S += part[ib * M_TOT + j];        // coalesced across threads

    const int k = j >> 10, l = j & (EPS_N - 1);
    const float omT = 1.0f - T;
    const float e0 = omT * emb[2 * k]     + T * eps[2 * l];
    const float e1 = omT * emb[2 * k + 1] + T * eps[2 * l + 1];
    const float g  = LOG2E * alpha * (e0 * e0 + e1 * e1);  // factored-out 2^g

    float v = g + LOG2F_(S);              // lse_j / ln2

#pragma unroll
    for (int off = 32; off; off >>= 1) v += __shfl_down(v, off, 64);
    __shared__ float wsum[BLOCK / 64];
    const int lane = threadIdx.x & 63, w = threadIdx.x >> 6;
    if (lane == 0) wsum[w] = v;
    __syncthreads();
    if (threadIdx.x == 0)
        bsum[blockIdx.x] = wsum[0] + wsum[1] + wsum[2] + wsum[3];
}

// Kernel 3: single wave — assemble scalar loss
__global__ void final_kernel(const float* __restrict__ log_sigma,
                             const float* __restrict__ bsum,
                             float* __restrict__ out)
{
    float v = bsum[threadIdx.x];          // exactly 64 block sums
#pragma unroll
    for (int off = 32; off; off >>= 1) v += __shfl_down(v, off, 64);
    if (threadIdx.x == 0) {
        const float ls = log_sigma[0];
        const float sum_lse = v * LN2;    // sum_j lse_j
        // loss = -mean(lse) + 0.5*z_dim*(2*ls - 1) + log(n);  z_dim=2, n=8192
        out[0] = -sum_lse / (float)M_TOT + (2.0f * ls - 1.0f) + 9.010913347279288f;
    }
}

extern "C" void kernel_launch(void* const* d_in, const int* in_sizes, int n_in,
                              void* d_out, int out_size, void* d_ws, size_t ws_size,
                              hipStream_t stream)
{
    const float* z    = (const float*)d_in[0];
    const float* emb  = (const float*)d_in[1];
    const float* lsig = (const float*)d_in[2];
    const float* eps  = (const float*)d_in[3];
    const float* temp = (const float*)d_in[4];

    float* part = (float*)d_ws;                    // NICH * M_TOT floats = 4 MB
    float* bsum = part + (size_t)NICH * M_TOT;     // 64 floats

    dim3 grid1(NLCH, NICH);                        // 8 x 64 = 512 blocks
    gemm_partial_kernel<<<grid1, BLOCK, 0, stream>>>(z, emb, lsig, eps, temp, part);
    reduce_kernel<<<M_TOT / BLOCK, BLOCK, 0, stream>>>(emb, lsig, eps, temp, part, bsum);
    final_kernel<<<1, 64, 0, stream>>>(lsig, bsum, (float*)d_out);
}